// Round 14
// baseline (5050.945 us; speedup 1.0000x reference)
//
#include <hip/hip_runtime.h>
#include <stdint.h>

typedef _Float16 f16;
typedef __attribute__((ext_vector_type(2))) _Float16 f16x2;
typedef __attribute__((ext_vector_type(4))) _Float16 f16x4;
typedef __attribute__((ext_vector_type(8))) _Float16 f16x8;
typedef __attribute__((ext_vector_type(4))) float f32x4;

#define TT 512
#define FF 3
#define HH 128
#define BB 16384
#define BC 32          // batch rows per block -> 512 blocks, 1 per CU (LDS-forced), 2 rounds
#define PITCH 296      // hc row pitch in f16
#define NTH 512        // 8 waves, col-split, m=2
#define WP 40          // wlds row pitch in f16
#define FCP 12         // fcw_s row pitch in floats (2-way banks, 16B aligned)

// Packed weights: Bp[grp(13)][gate(4)][col(128)][ksub(4)][e(8)] f16
//   grp 0..4  : layer0, K=160 (128 h0 | 3 data | delta@131 | bias0@132 | zeros)
//   grp 5..12 : layer1, K=256 (128 h0' + 128 h1)
// groups 0..9 in unified regs (160), 10..12 in LDS.
// Gates computed TRANSPOSED: mfma(W_frag, h_frag) -> packed b64 h stores.
#define NGRP 13
#define GSTRIDE 16384
#define NBP (NGRP*GSTRIDE)
#define WS_BIAS_OFF ((size_t)NBP*2)

__global__ void prep_kernel(
    const float* __restrict__ Wih0, const float* __restrict__ Whh0,
    const float* __restrict__ bih0, const float* __restrict__ bhh0,
    const float* __restrict__ Wih1, const float* __restrict__ Whh1,
    const float* __restrict__ bih1, const float* __restrict__ bhh1,
    f16* __restrict__ Bp, float* __restrict__ biasSum)
{
  int idx = blockIdx.x*256 + threadIdx.x;
  if (idx < NBP){
    int e = idx & 7, ksub = (idx>>3)&3, c = (idx>>5)&127, g = (idx>>12)&3, grp = idx>>14;
    int kl = ksub*8 + e;
    int gcol = g*128 + c;
    float v = 0.f;
    if (grp < 5){
      int k = grp*32 + kl;             // 0..159
      if (k < 128)       v = Whh0[gcol*128 + k];
      else if (k < 132)  v = Wih0[gcol*4 + (k - 128)];   // data0..2, delta@131
      else if (k == 132) v = bih0[gcol] + bhh0[gcol];    // bias0 row (ones col 260)
    } else {
      int k = (grp-5)*32 + kl;         // 0..255
      v = (k < 128) ? Wih1[gcol*128 + k] : Whh1[gcol*128 + (k - 128)];
    }
    Bp[idx] = (f16)v;
  } else if (idx < NBP + 1024){
    int j = idx - NBP;
    int layer = j >> 9, gcol = j & 511;
    biasSum[j] = layer ? (bih1[gcol] + bhh1[gcol]) : (bih0[gcol] + bhh0[gcol]);
  }
}

// fused LSTM element update with f16-packed c-state. 5 exp + 2 rcp.
__device__ __forceinline__ float cell_elem_p(float iv, float fv, float gv, float ov,
                                             f16x2* csa, int e){
  float cp = (float)csa[e>>1][e&1];
  float ea = __expf(-iv);
  float eb = __expf(2.f*gv);
  float ef = __expf(-fv);
  float A = 1.f + ea, Bq = 1.f + eb, F = 1.f + ef;
  float AB  = A*Bq;
  float num = cp*AB + (eb - 1.f)*F;
  float c   = num * __builtin_amdgcn_rcpf(AB*F);
  csa[e>>1][e&1] = (f16)c;
  float cc = fminf(fmaxf(c, -15.f), 15.f);
  float ew = __expf(2.f*cc);
  float eo = __expf(-ov);
  return (ew - 1.f) * __builtin_amdgcn_rcpf((1.f + eo)*(1.f + ew));
}

__global__ __launch_bounds__(NTH)
void lstm_kernel(
    const float* __restrict__ data, const float* __restrict__ PnL,
    const f16*  __restrict__ Bp,   const float* __restrict__ biasSum,
    const float* __restrict__ fcW, const float* __restrict__ fcb,
    const int* __restrict__ ploc,  float* __restrict__ out)
{
  // hc cols: [0,128) h0 | [128,256) h1 | [256,259) x | 259 delta | 260 ones | [261,296) zero
  __shared__ __align__(16) f16 hc[2*BC*PITCH];        // 37,888 B (double buffer)
  __shared__ __align__(16) f16 wlds[3*512*WP];        // 122,880 B (groups 10..12)
  __shared__ float fcw_s[16*FCP];                      // 768 B (padded pitch 12)
  __shared__ float dbuf[BC][16];                       // 2,048 B
  __shared__ float pnlbuf[BC];                         // 128 B
  // total 163,712 B -> 1 block/CU -> 2 waves/SIMD -> 256 unified regs/wave

  const int tid = threadIdx.x;
  const int w   = tid >> 6;
  const int l   = tid & 63;
  const int l15 = l & 15;
  const int lhi = l >> 4;
  const int jc  = w*16 + l15;        // weight-fragment column
  const int jcT = w*16 + lhi*4;      // transposed-output column base (4 consecutive)
  const int bg0 = blockIdx.x * BC;

  for (int i = tid; i < 2*BC*PITCH; i += NTH) hc[i] = (f16)0.f;
  if (tid < HH) fcw_s[(tid>>3)*FCP + (tid&7)] = fcW[tid];

  // stage weight groups 10..12 into LDS (once)
  for (int i = tid; i < 3*4*128*4; i += NTH){
    int ksub = i & 3, col = (i>>2)&127, g = (i>>9)&3, grp3 = i>>11;
    *(f16x8*)&wlds[((grp3*512) + g*128 + col)*WP + ksub*8] =
      *(const f16x8*)(Bp + (10+grp3)*GSTRIDE + g*4096 + col*32 + ksub*8);
  }

  float bias1[4];
#pragma unroll
  for (int g = 0; g < 4; ++g)
    bias1[g] = biasSum[512 + g*HH + jc];   // lane-splat at acc-init (transposed layout
                                           // needs per-col bias -> read at jcT+r below)
  f32x4 bias1v;
  {
    // per-lane 4 consecutive cols' bias for gate g handled via one vector each init;
    // store the 4 gate rows compactly: reload as needed (registers: 4)
  }
  // (we keep scalar bias1[g] for the lane's fragment column jc; the transposed acc
  //  init needs bias at cols jcT..jcT+3 per gate -> fetch once into 4 f32x4? too many
  //  regs; instead read the 4-wide vector per gate from LDS-free global ONCE:)
  f32x4 b1v[4];
#pragma unroll
  for (int g = 0; g < 4; ++g)
    b1v[g] = *(const f32x4*)&biasSum[512 + g*HH + jcT];
  // NOTE: b1v is the live one (16 regs); bias1[] above is dead and will be DCE'd.

  const float fcb0 = fcb[0];
  const int   pl   = ploc[0];

  // persistent weights: groups 0..9 -> 160 unified regs
  f16x8 wr[10][4];
  {
    const f16* BpL = Bp + jc*32 + lhi*8;
#pragma unroll
    for (int grp = 0; grp < 10; ++grp)
#pragma unroll
      for (int g = 0; g < 4; ++g)
        wr[grp][g] = *(const f16x8*)(BpL + grp*GSTRIDE + g*4096);
  }

  __syncthreads();
  // ones col 260 (bias0 row) in BOTH buffers; x(0) into buffer 0; zero out[:,0]
  if (tid < BC){
    hc[tid*PITCH + 260]            = (f16)1.f;
    hc[BC*PITCH + tid*PITCH + 260] = (f16)1.f;
  }
  if (tid < 128 && (tid & 3))
    hc[(tid>>2)*PITCH + 255 + (tid&3)] = (f16)data[(size_t)(bg0 + (tid>>2))*TT*FF + (tid&3) - 1];
  if (tid < BC) __builtin_nontemporal_store(0.f, &out[(size_t)(bg0 + tid)*513]);

  const int rowD = tid >> 4;   // delta-phase row 0..31
  const int subD = tid & 15;   // 16 lanes/row, 8 cols each

  f16x2 cs0[4], cs1[4];
#pragma unroll
  for (int e = 0; e < 4; ++e){
    f16x2 z = {(f16)0.f, (f16)0.f};
    cs0[e] = z; cs1[e] = z;
  }
  float pnl = 0.f, dold = 0.f;

  __syncthreads();

  for (int t = 0; t < TT; ++t){
    const f16* Ab = &hc[(t & 1) * (BC*PITCH)];        // read buffer
    f16*       Qb = &hc[((t & 1) ^ 1) * (BC*PITCH)];  // write buffer

    // flush previous 16-step delta window as coalesced stores
    if (t && !(t & 15))
      __builtin_nontemporal_store(dbuf[rowD][subD],
          &out[(size_t)(bg0 + rowD)*513 + (t - 15) + subD]);

    // hoist this step's tiny global loads
    float price_r = 0.f;
    if (subD == 0)
      price_r = data[(size_t)((bg0 + rowD)*TT + t)*FF + pl];
    float xnv = 0.f;
    const bool do_stage = (t < TT-1) && (tid < 128) && (tid & 3);
    if (do_stage)
      xnv = data[(size_t)((bg0 + (tid>>2))*TT + (t+1))*FF + (tid&3) - 1];

    f32x4 acc[2][4];
    // ========== G0: gates0^T = W0 @ [h0(t-1), x(t), delta, 1]^T  (reg groups 0..4) ======
#pragma unroll
    for (int g = 0; g < 4; ++g){
      f32x4 z = {0.f, 0.f, 0.f, 0.f};   // bias0 enters via ones-column
      acc[0][g] = z; acc[1][g] = z;
    }
#pragma unroll
    for (int ks = 0; ks < 5; ++ks){
      const int colA = (ks < 4 ? ks*32 : 256) + 8*lhi;
#pragma unroll
      for (int m = 0; m < 2; ++m){
        f16x8 a = *(const f16x8*)&Ab[(m*16 + l15)*PITCH + colA];
#pragma unroll
        for (int g = 0; g < 4; ++g)
          acc[m][g] = __builtin_amdgcn_mfma_f32_16x16x32_f16(wr[ks][g], a, acc[m][g], 0, 0, 0);
      }
    }

    // ---- cross-barrier prefetch: G1's ks=4,5 A-frags read Ab.h1 (stable all step);
    //      issue now so they drain under cell0 + B1 ----
    f16x8 pre[2][2];
#pragma unroll
    for (int q = 0; q < 2; ++q){
      const int colA = (4 + q)*32 + 8*lhi;
      pre[q][0] = *(const f16x8*)&Ab[(l15)*PITCH + colA];
      pre[q][1] = *(const f16x8*)&Ab[(16 + l15)*PITCH + colA];
    }

    // ========== cell 0 -> packed b64 writes ==========
#pragma unroll
    for (int m = 0; m < 2; ++m){
      f16x4 hv;
#pragma unroll
      for (int r = 0; r < 4; ++r)
        hv[r] = (f16)cell_elem_p(acc[m][0][r], acc[m][1][r], acc[m][2][r], acc[m][3][r], cs0, m*4+r);
      *(f16x4*)&Qb[(m*16 + l15)*PITCH + jcT] = hv;
    }
    __syncthreads();   // (B1) h0(t) visible

    // ========== G1: gates1^T = W1 @ [h0(t), h1(t-1)]^T ==========
#pragma unroll
    for (int g = 0; g < 4; ++g){
      acc[0][g] = b1v[g]; acc[1][g] = b1v[g];
    }
#pragma unroll
    for (int ks = 0; ks < 8; ++ks){
      f16x8 a0, a1;
      if (ks == 4){ a0 = pre[0][0]; a1 = pre[0][1]; }
      else if (ks == 5){ a0 = pre[1][0]; a1 = pre[1][1]; }
      else {
        const f16* ap   = (ks < 4) ? Qb : Ab;   // h0(t) then h1(t-1)
        const int  colA = ks*32 + 8*lhi;
        a0 = *(const f16x8*)&ap[(l15)*PITCH + colA];
        a1 = *(const f16x8*)&ap[(16 + l15)*PITCH + colA];
      }
#pragma unroll
      for (int g = 0; g < 4; ++g){
        f16x8 bf;
        if (ks < 5) bf = wr[5 + ks][g];
        else        bf = *(const f16x8*)&wlds[(((ks-5)*512) + g*128 + jc)*WP + lhi*8];
        acc[0][g] = __builtin_amdgcn_mfma_f32_16x16x32_f16(bf, a0, acc[0][g], 0, 0, 0);
        acc[1][g] = __builtin_amdgcn_mfma_f32_16x16x32_f16(bf, a1, acc[1][g], 0, 0, 0);
      }
    }

    // ========== cell 1 -> packed b64 writes ==========
#pragma unroll
    for (int m = 0; m < 2; ++m){
      f16x4 hv;
#pragma unroll
      for (int r = 0; r < 4; ++r)
        hv[r] = (f16)cell_elem_p(acc[m][0][r], acc[m][1][r], acc[m][2][r], acc[m][3][r], cs1, m*4+r);
      *(f16x4*)&Qb[(m*16 + l15)*PITCH + 128 + jcT] = hv;
    }
    __syncthreads();   // (B2) h1(t) visible

    // ========== delta = h1(t) @ fcW^T + fcb ; pnl ; stage x(t+1) ==========
    {
      f16x8 v = *(const f16x8*)&Qb[rowD*PITCH + 128 + subD*8];
      f32x4 f0 = *(const f32x4*)&fcw_s[subD*FCP];
      f32x4 f1 = *(const f32x4*)&fcw_s[subD*FCP + 4];
      float s = (float)v[0]*f0[0] + (float)v[1]*f0[1] + (float)v[2]*f0[2] + (float)v[3]*f0[3]
              + (float)v[4]*f1[0] + (float)v[5]*f1[1] + (float)v[6]*f1[2] + (float)v[7]*f1[3];
      s += __shfl_xor(s, 1);
      s += __shfl_xor(s, 2);
      s += __shfl_xor(s, 4);
      s += __shfl_xor(s, 8);
      if (subD == 0){
        const float dnew = s + fcb0;
        pnl += (dold - dnew) * price_r;
        dbuf[rowD][t & 15] = dnew;
        Qb[rowD*PITCH + 259] = (f16)dnew;
        dold = dnew;
        if (t == TT-1){
          const float lastp = data[(size_t)((bg0 + rowD)*TT + (TT-1))*FF + 0];
          pnlbuf[rowD] = pnl + dnew*lastp;
        }
      }
      if (do_stage)
        Qb[(tid>>2)*PITCH + 255 + (tid&3)] = (f16)xnv;
    }
    __syncthreads();   // (B3) Qb complete -> becomes read buffer
  }

  // final window flush (out cols 497..512) and pnl
  __builtin_nontemporal_store(dbuf[rowD][subD],
      &out[(size_t)(bg0 + rowD)*513 + 497 + subD]);
  if (tid < BC)
    out[(size_t)BB*513 + bg0 + tid] = pnlbuf[tid] + PnL[bg0 + tid];
}

extern "C" void kernel_launch(void* const* d_in, const int* in_sizes, int n_in,
                              void* d_out, int out_size, void* d_ws, size_t ws_size,
                              hipStream_t stream)
{
  const float* data = (const float*)d_in[0];
  const float* PnL  = (const float*)d_in[1];
  const float* Wih0 = (const float*)d_in[2];
  const float* Whh0 = (const float*)d_in[3];
  const float* bih0 = (const float*)d_in[4];
  const float* bhh0 = (const float*)d_in[5];
  const float* Wih1 = (const float*)d_in[6];
  const float* Whh1 = (const float*)d_in[7];
  const float* bih1 = (const float*)d_in[8];
  const float* bhh1 = (const float*)d_in[9];
  const float* fcW  = (const float*)d_in[10];
  const float* fcb  = (const float*)d_in[11];
  const int*   ploc = (const int*)d_in[12];

  f16*   Bp      = (f16*)d_ws;
  float* biasSum = (float*)((char*)d_ws + WS_BIAS_OFF);
  float* out     = (float*)d_out;

  const int prepN = NBP + 1024;
  prep_kernel<<<(prepN + 255)/256, 256, 0, stream>>>(
      Wih0, Whh0, bih0, bhh0, Wih1, Whh1, bih1, bhh1, Bp, biasSum);
  lstm_kernel<<<BB/BC, NTH, 0, stream>>>(
      data, PnL, Bp, biasSum, fcW, fcb, ploc, out);
}

// Round 15
// 4441.068 us; speedup vs baseline: 1.1373x; 1.1373x over previous
//
#include <hip/hip_runtime.h>
#include <stdint.h>

typedef _Float16 f16;
typedef __attribute__((ext_vector_type(2))) _Float16 f16x2;
typedef __attribute__((ext_vector_type(4))) _Float16 f16x4;
typedef __attribute__((ext_vector_type(8))) _Float16 f16x8;
typedef __attribute__((ext_vector_type(4))) float f32x4;

#define TT 512
#define FF 3
#define HH 128
#define BB 16384
#define BC 32          // batch rows per block -> 512 blocks, 1 per CU (LDS-forced), 2 rounds
#define PITCH 296      // hc row pitch in f16 (148 dw; b128 quad-starts cover all banks -> optimal)
#define NTH 512        // 8 waves, col-split, m=2
#define WP 40          // wlds row pitch in f16
#define FCP 12         // fcw_s row pitch in floats (breaks the 4-way subD*8 pattern)

// Packed weights: Bp[grp(13)][gate(4)][col(128)][ksub(4)][e(8)] f16
//   grp 0..4  : layer0, K=160 (128 h0 | 3 data | delta@131 | bias0@132 | zeros)
//   grp 5..12 : layer1, K=256 (128 h0' + 128 h1)
// groups 0..9 in unified regs (160), 10..12 in LDS.
// Gates computed TRANSPOSED: mfma(W_frag, h_frag) -> packed b64 h stores.
#define NGRP 13
#define GSTRIDE 16384
#define NBP (NGRP*GSTRIDE)
#define WS_BIAS_OFF ((size_t)NBP*2)

__global__ void prep_kernel(
    const float* __restrict__ Wih0, const float* __restrict__ Whh0,
    const float* __restrict__ bih0, const float* __restrict__ bhh0,
    const float* __restrict__ Wih1, const float* __restrict__ Whh1,
    const float* __restrict__ bih1, const float* __restrict__ bhh1,
    f16* __restrict__ Bp, float* __restrict__ biasSum)
{
  int idx = blockIdx.x*256 + threadIdx.x;
  if (idx < NBP){
    int e = idx & 7, ksub = (idx>>3)&3, c = (idx>>5)&127, g = (idx>>12)&3, grp = idx>>14;
    int kl = ksub*8 + e;
    int gcol = g*128 + c;
    float v = 0.f;
    if (grp < 5){
      int k = grp*32 + kl;             // 0..159
      if (k < 128)       v = Whh0[gcol*128 + k];
      else if (k < 132)  v = Wih0[gcol*4 + (k - 128)];   // data0..2, delta@131
      else if (k == 132) v = bih0[gcol] + bhh0[gcol];    // bias0 row (ones col 260)
    } else {
      int k = (grp-5)*32 + kl;         // 0..255
      v = (k < 128) ? Wih1[gcol*128 + k] : Whh1[gcol*128 + (k - 128)];
    }
    Bp[idx] = (f16)v;
  } else if (idx < NBP + 1024){
    int j = idx - NBP;
    int layer = j >> 9, gcol = j & 511;
    biasSum[j] = layer ? (bih1[gcol] + bhh1[gcol]) : (bih0[gcol] + bhh0[gcol]);
  }
}

// fused LSTM element update with f16-packed c-state. 5 exp + 2 rcp.
__device__ __forceinline__ float cell_elem_p(float iv, float fv, float gv, float ov,
                                             f16x2* csa, int e){
  float cp = (float)csa[e>>1][e&1];
  float ea = __expf(-iv);
  float eb = __expf(2.f*gv);
  float ef = __expf(-fv);
  float A = 1.f + ea, Bq = 1.f + eb, F = 1.f + ef;
  float AB  = A*Bq;
  float num = cp*AB + (eb - 1.f)*F;
  float c   = num * __builtin_amdgcn_rcpf(AB*F);
  csa[e>>1][e&1] = (f16)c;
  float cc = fminf(fmaxf(c, -15.f), 15.f);
  float ew = __expf(2.f*cc);
  float eo = __expf(-ov);
  return (ew - 1.f) * __builtin_amdgcn_rcpf((1.f + eo)*(1.f + ew));
}

__global__ __launch_bounds__(NTH)
void lstm_kernel(
    const float* __restrict__ data, const float* __restrict__ PnL,
    const f16*  __restrict__ Bp,   const float* __restrict__ biasSum,
    const float* __restrict__ fcW, const float* __restrict__ fcb,
    const int* __restrict__ ploc,  float* __restrict__ out)
{
  // hc cols: [0,128) h0 | [128,256) h1 | [256,259) x | 259 delta | 260 ones | [261,296) zero
  __shared__ __align__(16) f16 hc[2*BC*PITCH];        // 37,888 B (double buffer)
  __shared__ __align__(16) f16 wlds[3*512*WP];        // 122,880 B (groups 10..12)
  __shared__ float fcw_s[16*FCP];                      // 768 B (padded pitch 12)
  __shared__ float dbuf[BC][16];                       // 2,048 B
  __shared__ float pnlbuf[BC];                         // 128 B
  // total 163,712 B -> 1 block/CU -> 2 waves/SIMD -> 256 unified regs/wave

  const int tid = threadIdx.x;
  const int w   = tid >> 6;
  const int l   = tid & 63;
  const int l15 = l & 15;
  const int lhi = l >> 4;
  const int jc  = w*16 + l15;        // weight-fragment column
  const int jcT = w*16 + lhi*4;      // transposed-output column base (4 consecutive)
  const int bg0 = blockIdx.x * BC;

  for (int i = tid; i < 2*BC*PITCH; i += NTH) hc[i] = (f16)0.f;
  if (tid < HH) fcw_s[(tid>>3)*FCP + (tid&7)] = fcW[tid];

  // stage weight groups 10..12 into LDS (once)
  for (int i = tid; i < 3*4*128*4; i += NTH){
    int ksub = i & 3, col = (i>>2)&127, g = (i>>9)&3, grp3 = i>>11;
    *(f16x8*)&wlds[((grp3*512) + g*128 + col)*WP + ksub*8] =
      *(const f16x8*)(Bp + (10+grp3)*GSTRIDE + g*4096 + col*32 + ksub*8);
  }

  // vectorized bias1 over the lane's 4 consecutive gate-cols
  f32x4 bias1v[4];
#pragma unroll
  for (int g = 0; g < 4; ++g)
    bias1v[g] = *(const f32x4*)&biasSum[512 + g*HH + jcT];
  const float fcb0 = fcb[0];
  const int   pl   = ploc[0];

  // persistent weights: groups 0..9 -> 160 unified regs
  f16x8 wr[10][4];
  {
    const f16* BpL = Bp + jc*32 + lhi*8;
#pragma unroll
    for (int grp = 0; grp < 10; ++grp)
#pragma unroll
      for (int g = 0; g < 4; ++g)
        wr[grp][g] = *(const f16x8*)(BpL + grp*GSTRIDE + g*4096);
  }

  __syncthreads();
  // ones col 260 (bias0 row) in BOTH buffers; x(0) into buffer 0; zero out[:,0]
  if (tid < BC){
    hc[tid*PITCH + 260]            = (f16)1.f;
    hc[BC*PITCH + tid*PITCH + 260] = (f16)1.f;
  }
  if (tid < 128 && (tid & 3))
    hc[(tid>>2)*PITCH + 255 + (tid&3)] = (f16)data[(size_t)(bg0 + (tid>>2))*TT*FF + (tid&3) - 1];
  if (tid < BC) __builtin_nontemporal_store(0.f, &out[(size_t)(bg0 + tid)*513]);

  const int rowD = tid >> 4;   // delta-phase row 0..31
  const int subD = tid & 15;   // 16 lanes/row, 8 cols each

  f16x2 cs0[4], cs1[4];
#pragma unroll
  for (int e = 0; e < 4; ++e){
    f16x2 z = {(f16)0.f, (f16)0.f};
    cs0[e] = z; cs1[e] = z;
  }
  float pnl = 0.f, dold = 0.f;

  __syncthreads();

  for (int t = 0; t < TT; ++t){
    const f16* Ab = &hc[(t & 1) * (BC*PITCH)];        // read buffer
    f16*       Qb = &hc[((t & 1) ^ 1) * (BC*PITCH)];  // write buffer

    // flush previous 16-step delta window as coalesced stores
    if (t && !(t & 15))
      __builtin_nontemporal_store(dbuf[rowD][subD],
          &out[(size_t)(bg0 + rowD)*513 + (t - 15) + subD]);

    // hoist this step's tiny global loads
    float price_r = 0.f;
    if (subD == 0)
      price_r = data[(size_t)((bg0 + rowD)*TT + t)*FF + pl];
    float xnv = 0.f;
    const bool do_stage = (t < TT-1) && (tid < 128) && (tid & 3);
    if (do_stage)
      xnv = data[(size_t)((bg0 + (tid>>2))*TT + (t+1))*FF + (tid&3) - 1];

    f32x4 acc[2][4];
    // ========== G0: gates0^T = W0 @ [h0(t-1), x(t), delta, 1]^T  (reg groups 0..4) ======
#pragma unroll
    for (int g = 0; g < 4; ++g){
      f32x4 z = {0.f, 0.f, 0.f, 0.f};   // bias0 enters via ones-column
      acc[0][g] = z; acc[1][g] = z;
    }
#pragma unroll
    for (int ks = 0; ks < 5; ++ks){
      const int colA = (ks < 4 ? ks*32 : 256) + 8*lhi;
#pragma unroll
      for (int m = 0; m < 2; ++m){
        f16x8 a = *(const f16x8*)&Ab[(m*16 + l15)*PITCH + colA];
#pragma unroll
        for (int g = 0; g < 4; ++g)
          acc[m][g] = __builtin_amdgcn_mfma_f32_16x16x32_f16(wr[ks][g], a, acc[m][g], 0, 0, 0);
      }
    }

    // ========== cell 0 -> packed b64 writes ==========
#pragma unroll
    for (int m = 0; m < 2; ++m){
      f16x4 hv;
#pragma unroll
      for (int r = 0; r < 4; ++r)
        hv[r] = (f16)cell_elem_p(acc[m][0][r], acc[m][1][r], acc[m][2][r], acc[m][3][r], cs0, m*4+r);
      *(f16x4*)&Qb[(m*16 + l15)*PITCH + jcT] = hv;
    }
    __syncthreads();   // (B1) h0(t) visible

    // ========== G1: gates1^T = W1 @ [h0(t), h1(t-1)]^T ==========
#pragma unroll
    for (int g = 0; g < 4; ++g){
      acc[0][g] = bias1v[g]; acc[1][g] = bias1v[g];
    }
#pragma unroll
    for (int ks = 0; ks < 8; ++ks){
      const f16* ap   = (ks < 4) ? Qb : Ab;   // h0(t) then h1(t-1)
      const int  colA = ks*32 + 8*lhi;
      f16x8 a0 = *(const f16x8*)&ap[(l15)*PITCH + colA];
      f16x8 a1 = *(const f16x8*)&ap[(16 + l15)*PITCH + colA];
#pragma unroll
      for (int g = 0; g < 4; ++g){
        f16x8 bf;
        if (ks < 5) bf = wr[5 + ks][g];
        else        bf = *(const f16x8*)&wlds[(((ks-5)*512) + g*128 + jc)*WP + lhi*8];
        acc[0][g] = __builtin_amdgcn_mfma_f32_16x16x32_f16(bf, a0, acc[0][g], 0, 0, 0);
        acc[1][g] = __builtin_amdgcn_mfma_f32_16x16x32_f16(bf, a1, acc[1][g], 0, 0, 0);
      }
    }

    // ========== cell 1 -> packed b64 writes ==========
#pragma unroll
    for (int m = 0; m < 2; ++m){
      f16x4 hv;
#pragma unroll
      for (int r = 0; r < 4; ++r)
        hv[r] = (f16)cell_elem_p(acc[m][0][r], acc[m][1][r], acc[m][2][r], acc[m][3][r], cs1, m*4+r);
      *(f16x4*)&Qb[(m*16 + l15)*PITCH + 128 + jcT] = hv;
    }
    __syncthreads();   // (B2) h1(t) visible

    // ========== delta = h1(t) @ fcW^T + fcb ; pnl ; stage x(t+1) ==========
    {
      f16x8 v = *(const f16x8*)&Qb[rowD*PITCH + 128 + subD*8];
      f32x4 f0 = *(const f32x4*)&fcw_s[subD*FCP];
      f32x4 f1 = *(const f32x4*)&fcw_s[subD*FCP + 4];
      float s = (float)v[0]*f0[0] + (float)v[1]*f0[1] + (float)v[2]*f0[2] + (float)v[3]*f0[3]
              + (float)v[4]*f1[0] + (float)v[5]*f1[1] + (float)v[6]*f1[2] + (float)v[7]*f1[3];
      s += __shfl_xor(s, 1);
      s += __shfl_xor(s, 2);
      s += __shfl_xor(s, 4);
      s += __shfl_xor(s, 8);
      if (subD == 0){
        const float dnew = s + fcb0;
        pnl += (dold - dnew) * price_r;
        dbuf[rowD][t & 15] = dnew;
        Qb[rowD*PITCH + 259] = (f16)dnew;
        dold = dnew;
        if (t == TT-1){
          const float lastp = data[(size_t)((bg0 + rowD)*TT + (TT-1))*FF + 0];
          pnlbuf[rowD] = pnl + dnew*lastp;
        }
      }
      if (do_stage)
        Qb[(tid>>2)*PITCH + 255 + (tid&3)] = (f16)xnv;
    }
    __syncthreads();   // (B3) Qb complete -> becomes read buffer
  }

  // final window flush (out cols 497..512) and pnl
  __builtin_nontemporal_store(dbuf[rowD][subD],
      &out[(size_t)(bg0 + rowD)*513 + 497 + subD]);
  if (tid < BC)
    out[(size_t)BB*513 + bg0 + tid] = pnlbuf[tid] + PnL[bg0 + tid];
}

extern "C" void kernel_launch(void* const* d_in, const int* in_sizes, int n_in,
                              void* d_out, int out_size, void* d_ws, size_t ws_size,
                              hipStream_t stream)
{
  const float* data = (const float*)d_in[0];
  const float* PnL  = (const float*)d_in[1];
  const float* Wih0 = (const float*)d_in[2];
  const float* Whh0 = (const float*)d_in[3];
  const float* bih0 = (const float*)d_in[4];
  const float* bhh0 = (const float*)d_in[5];
  const float* Wih1 = (const float*)d_in[6];
  const float* Whh1 = (const float*)d_in[7];
  const float* bih1 = (const float*)d_in[8];
  const float* bhh1 = (const float*)d_in[9];
  const float* fcW  = (const float*)d_in[10];
  const float* fcb  = (const float*)d_in[11];
  const int*   ploc = (const int*)d_in[12];

  f16*   Bp      = (f16*)d_ws;
  float* biasSum = (float*)((char*)d_ws + WS_BIAS_OFF);
  float* out     = (float*)d_out;

  const int prepN = NBP + 1024;
  prep_kernel<<<(prepN + 255)/256, 256, 0, stream>>>(
      Wih0, Whh0, bih0, bhh0, Wih1, Whh1, bih1, bhh1, Bp, biasSum);
  lstm_kernel<<<BB/BC, NTH, 0, stream>>>(
      data, PnL, Bp, biasSum, fcW, fcb, ploc, out);
}